// Round 2
// baseline (390.437 us; speedup 1.0000x reference)
//
#include <hip/hip_runtime.h>
#include <math.h>

#define NPTS   500000
#define NB     256
#define TOPK   10
#define CAP    2048
#define SPER   64          // sample points per slice; 256 slices -> 16384 sample
#define MARGIN 2.0f        // bf16 worst-case score err ~0.6; 3x headroom
#define FPTS   128         // points per k_filter block
#define FGRID  ((NPTS + FPTS - 1) / FPTS)   // 3907
#define QS     52          // LDS row stride in bf16 (104 B: 8-B aligned, 2-way banks)

typedef short v4s  __attribute__((ext_vector_type(4)));
typedef short v8s  __attribute__((ext_vector_type(8)));
typedef float v16f __attribute__((ext_vector_type(16)));

__device__ __forceinline__ unsigned short f2bf(float f) {   // round-to-nearest-even
    unsigned u = __float_as_uint(f);
    unsigned r = u + 0x7FFFu + ((u >> 16) & 1u);
    return (unsigned short)(r >> 16);
}
__device__ __forceinline__ float bf2f(unsigned short h) {
    return __uint_as_float(((unsigned)h) << 16);
}

// --- exact fp32 pieces: bitwise-identical in k_sample and k_final -----------
__device__ __forceinline__ float norm34(const float* __restrict__ r) {
    float a0 = 0.f, a1 = 0.f, a2 = 0.f, a3 = 0.f;
#pragma unroll
    for (int d = 0; d < 32; d += 4) {
        a0 = fmaf(r[d + 0], r[d + 0], a0);
        a1 = fmaf(r[d + 1], r[d + 1], a1);
        a2 = fmaf(r[d + 2], r[d + 2], a2);
        a3 = fmaf(r[d + 3], r[d + 3], a3);
    }
    a0 = fmaf(r[32], r[32], a0);
    a1 = fmaf(r[33], r[33], a1);
    return (a0 + a1) + (a2 + a3);
}
__device__ __forceinline__ float dot34(const float* __restrict__ r, const float* q) {
    float a0 = 0.f, a1 = 0.f, a2 = 0.f, a3 = 0.f;
#pragma unroll
    for (int d = 0; d < 32; d += 4) {
        a0 = fmaf(r[d + 0], q[d + 0], a0);
        a1 = fmaf(r[d + 1], q[d + 1], a1);
        a2 = fmaf(r[d + 2], q[d + 2], a2);
        a3 = fmaf(r[d + 3], q[d + 3], a3);
    }
    a0 = fmaf(r[32], q[32], a0);
    a1 = fmaf(r[33], q[33], a1);
    return (a0 + a1) + (a2 + a3);
}
__device__ __forceinline__ void load_q(const float* __restrict__ obs,
                                       const float* __restrict__ act, int b, float* q) {
#pragma unroll
    for (int d = 0; d < 32; ++d) q[d] = obs[b * 32 + d];
    q[32] = act[b * 2 + 0];
    q[33] = act[b * 2 + 1];
}

// --- kernel 0a: per-(query, 64-pt slice) min of s over 16384-pt sample ------
// LDS-staged so the j-loop reads broadcast LDS, not latency-bound global.
__global__ __launch_bounds__(256, 4) void k_sample(const float* __restrict__ obs,
                                                   const float* __restrict__ act,
                                                   const float* __restrict__ msa,
                                                   float* __restrict__ minima) {
    __shared__ __align__(16) float sm[SPER * 36];   // stride 36 -> 16-B aligned rows
    __shared__ float smn[SPER];
    const int g = blockIdx.x, t = threadIdx.x;
    const int base = g * SPER;
    for (int i = t; i < SPER * 34; i += 256) {      // coalesced copy
        int row = i / 34, d = i - row * 34;
        sm[row * 36 + d] = msa[(size_t)base * 34 + i];
    }
    __syncthreads();
    if (t < SPER) smn[t] = norm34(&sm[t * 36]);     // exact fp32 norms
    __syncthreads();
    float q[34];
    load_q(obs, act, t, q);
    float best = __builtin_inff();
#pragma unroll 2
    for (int j = 0; j < SPER; ++j) {
        float s = fmaf(-2.f, dot34(&sm[j * 36], q), smn[j]);
        best = fminf(best, s);
    }
    minima[g * NB + t] = best;
}

// --- kernel 0b: tau = 10th smallest slice-min; zero counts; emit q-hat bf16 -
// q-hat = [q(34), -0.5, (tau+MARGIN)/2, 0...] so filter condition is acc >= 0.
__global__ __launch_bounds__(64) void k_tau(const float* __restrict__ minima,
                                            const float* __restrict__ obs,
                                            const float* __restrict__ act,
                                            unsigned short* __restrict__ qbf,
                                            int* __restrict__ count) {
    const int b = blockIdx.x, lane = threadIdx.x;
    if (lane == 0) count[b] = 0;
    float v[4];
#pragma unroll
    for (int k = 0; k < 4; ++k) v[k] = minima[(lane + 64 * k) * NB + b];
    float last = 0.f;
    for (int r = 0; r < TOPK; ++r) {
        float lm = v[0]; int la = 0;
#pragma unroll
        for (int k = 1; k < 4; ++k) { if (v[k] < lm) { lm = v[k]; la = k; } }
        float wm = lm;
        for (int off = 32; off; off >>= 1) wm = fminf(wm, __shfl_xor(wm, off));
        unsigned long long msk = __ballot(lm == wm);
        int first = (int)__builtin_ctzll(msk);
        if (lane == first) {
#pragma unroll
            for (int k = 0; k < 4; ++k) { if (k == la) v[k] = __builtin_inff(); }
        }
        last = wm;   // wave-uniform
    }
    // q-hat write (lanes 0..51)
    float val = 0.f;
    if (lane < 32)       val = obs[b * 32 + lane];
    else if (lane < 34)  val = act[b * 2 + (lane - 32)];
    else if (lane == 34) val = -0.5f;
    else if (lane == 35) val = 0.5f * (last + MARGIN);
    unsigned short h = (lane < 36) ? f2bf(val) : (unsigned short)0;
    if (lane < QS) qbf[b * QS + lane] = h;
}

// --- kernel 1: MFMA bf16 filter. acc[q][p] = q.m - 0.5*|m|^2 + (tau_q+M)/2 --
// append p as candidate for q iff acc >= 0  (i.e. s <= tau_q + MARGIN)
__global__ __launch_bounds__(256, 4) void k_filter(const float* __restrict__ msa,
                                                   const unsigned short* __restrict__ qbf,
                                                   int* __restrict__ count,
                                                   int* __restrict__ cand_i) {
    __shared__ __align__(16) unsigned short lq[NB * QS];    // 26624 B
    __shared__ __align__(16) unsigned short lm[FPTS * QS];  // 13312 B
    const int g = blockIdx.x, t = threadIdx.x;
    const int lo = g * FPTS;
    // stage Q-hat (pre-converted bf16): 26624 B as float4
    const float4* qsrc = (const float4*)qbf;
    for (int i = t; i < NB * QS / 8; i += 256)
        *(float4*)&lq[i * 8] = qsrc[i];
    // stage M chunk: 128 rows x 17 float2-pairs, convert to bf16
    for (int i = t; i < FPTS * 17; i += 256) {
        int row = i / 17, dp = i - row * 17;
        int gp = lo + row;
        float2 v = make_float2(0.f, 0.f);
        if (gp < NPTS) v = *(const float2*)&msa[(size_t)gp * 34 + 2 * dp];
        ushort2 h; h.x = f2bf(v.x); h.y = f2bf(v.y);
        *(ushort2*)&lm[row * QS + 2 * dp] = h;
    }
    __syncthreads();
    // norm pass: |m|^2 of the bf16 values (what MFMA sees), +1 bias dim, zero pad
    if (t < FPTS) {
        float nrm = 0.f;
#pragma unroll
        for (int dp = 0; dp < 17; ++dp) {
            ushort2 h = *(const ushort2*)&lm[t * QS + 2 * dp];
            float f0 = bf2f(h.x), f1 = bf2f(h.y);
            nrm = fmaf(f0, f0, nrm);
            nrm = fmaf(f1, f1, nrm);
        }
        bool valid = (lo + t < NPTS);
        lm[t * QS + 34] = f2bf(valid ? nrm : 1e30f);                  // norm dim
        lm[t * QS + 35] = valid ? (unsigned short)0x3F80 : (unsigned short)0; // bias=1.0
        *(ushort4*)&lm[t * QS + 36] = make_ushort4(0, 0, 0, 0);
        *(ushort4*)&lm[t * QS + 40] = make_ushort4(0, 0, 0, 0);
        *(ushort4*)&lm[t * QS + 44] = make_ushort4(0, 0, 0, 0);
    }
    __syncthreads();
    const int w = t >> 6, lane = t & 63;
    const int mrow = lane & 31, half = lane >> 5;
    for (int qi = 0; qi < 2; ++qi) {
        const int qt = w + 4 * qi;                 // q-tile 0..7
        const unsigned short* qrow = &lq[(qt * 32 + mrow) * QS + half * 8];
        v8s A[3];
#pragma unroll
        for (int s = 0; s < 3; ++s) {              // A[m=lane&31][k=(lane>>5)*8+j]
            v4s alo = *(const v4s*)(qrow + 16 * s);
            v4s ahi = *(const v4s*)(qrow + 16 * s + 4);
            A[s] = __builtin_shufflevector(alo, ahi, 0, 1, 2, 3, 4, 5, 6, 7);
        }
#pragma unroll
        for (int pt = 0; pt < FPTS / 32; ++pt) {
            const unsigned short* mrp = &lm[(pt * 32 + mrow) * QS + half * 8];
            v16f acc;
#pragma unroll
            for (int i = 0; i < 16; ++i) acc[i] = 0.f;
#pragma unroll
            for (int s = 0; s < 3; ++s) {
                v4s blo = *(const v4s*)(mrp + 16 * s);
                v4s bhi = *(const v4s*)(mrp + 16 * s + 4);
                v8s B = __builtin_shufflevector(blo, bhi, 0, 1, 2, 3, 4, 5, 6, 7);
                acc = __builtin_amdgcn_mfma_f32_32x32x16_bf16(A[s], B, acc, 0, 0, 0);
            }
            unsigned long long any = 0ull;
#pragma unroll
            for (int r = 0; r < 16; ++r) any |= __ballot(acc[r] >= 0.f);
            if (any) {                              // wave-uniform rare-ish path
                const int p = lo + pt * 32 + mrow;
#pragma unroll
                for (int r = 0; r < 16; ++r) {
                    if (acc[r] >= 0.f) {
                        // C/D: col(point)=lane&31, row(query)=(r&3)+8*(r>>2)+4*(lane>>5)
                        int qq = qt * 32 + (r & 3) + 8 * (r >> 2) + 4 * half;
                        int slot = atomicAdd(&count[qq], 1);
                        if (slot < CAP) cand_i[(size_t)qq * CAP + slot] = p;
                    }
                }
            }
        }
    }
}

// --- kernel 2: exact fp32 refine of candidates + top-10 + softmax -----------
__global__ __launch_bounds__(256) void k_final(const float* __restrict__ obs,
                                               const float* __restrict__ act,
                                               const float* __restrict__ msa,
                                               const int* __restrict__ cand_i,
                                               const int* __restrict__ count,
                                               const float* __restrict__ memQ,
                                               float* __restrict__ out) {
    __shared__ float ls[CAP];
    __shared__ int   li[CAP];
    __shared__ float rs[4];
    __shared__ int   ri[4];
    __shared__ float sel_s[TOPK];
    __shared__ int   sel_i[TOPK];
    const int b = blockIdx.x, t = threadIdx.x;
    const int lane = t & 63, wid = t >> 6;
    int cnt = count[b];
    if (cnt > CAP) cnt = CAP;
    float q[34];
    load_q(obs, act, b, q);
    for (int j = t; j < cnt; j += 256) {            // exact fp32 re-scores
        int idx = cand_i[(size_t)b * CAP + j];
        const float* row = msa + (size_t)idx * 34;
        ls[j] = fmaf(-2.f, dot34(row, q), norm34(row));
        li[j] = idx;
    }
    __syncthreads();
    for (int k = 0; k < TOPK; ++k) {
        float bs = __builtin_inff();
        int   bi = 0x7fffffff;
        for (int j = t; j < cnt; j += 256) {
            float s = ls[j]; int i = li[j];
            if (s < bs || (s == bs && i < bi)) { bs = s; bi = i; }
        }
        for (int off = 32; off; off >>= 1) {
            float s2 = __shfl_down(bs, off);
            int   i2 = __shfl_down(bi, off);
            if (s2 < bs || (s2 == bs && i2 < bi)) { bs = s2; bi = i2; }
        }
        if (lane == 0) { rs[wid] = bs; ri[wid] = bi; }
        __syncthreads();
        if (t == 0) {
            float fs = rs[0]; int fi = ri[0];
#pragma unroll
            for (int ww = 1; ww < 4; ++ww) {
                if (rs[ww] < fs || (rs[ww] == fs && ri[ww] < fi)) { fs = rs[ww]; fi = ri[ww]; }
            }
            sel_s[k] = fs; sel_i[k] = fi;
        }
        __syncthreads();
        const int win = sel_i[k];
        for (int j = t; j < cnt; j += 256) {
            if (li[j] == win) ls[j] = __builtin_inff();
        }
        __syncthreads();
    }
    if (t == 0) {
        float m = sel_s[TOPK - 1];
        float wsum = 0.f, acc = 0.f;
#pragma unroll
        for (int k = 0; k < TOPK; ++k) {
            if (sel_i[k] == 0x7fffffff) continue;
            float w2 = expf(sel_s[k] - m);
            wsum += w2;
            acc = fmaf(w2, memQ[sel_i[k]], acc);
        }
        out[b] = acc / wsum;
    }
}

extern "C" void kernel_launch(void* const* d_in, const int* in_sizes, int n_in,
                              void* d_out, int out_size, void* d_ws, size_t ws_size,
                              hipStream_t stream) {
    const float* obs = (const float*)d_in[0];   // [256,32]
    const float* act = (const float*)d_in[1];   // [256,2]
    const float* msa = (const float*)d_in[2];   // [500000,34]
    const float* mq  = (const float*)d_in[3];   // [500000,1]
    float* out = (float*)d_out;                 // [256]

    char* ws = (char*)d_ws;
    unsigned short* qbf = (unsigned short*)ws;              // 26624 B (16-B aligned)
    int*   count  = (int*)(ws + 26624);                     // 1024 B
    float* minima = (float*)(ws + 27648);                   // 262144 B
    int*   cand_i = (int*)(ws + 27648 + 262144);            // 2 MB
    // total ws use ~2.3 MB

    k_sample<<<NB, 256, 0, stream>>>(obs, act, msa, minima);
    k_tau   <<<NB, 64, 0, stream>>>(minima, obs, act, qbf, count);
    k_filter<<<FGRID, 256, 0, stream>>>(msa, qbf, count, cand_i);
    k_final <<<NB, 256, 0, stream>>>(obs, act, msa, cand_i, count, mq, out);
}

// Round 3
// 244.004 us; speedup vs baseline: 1.6001x; 1.6001x over previous
//
#include <hip/hip_runtime.h>
#include <math.h>

#define NPTS   500000
#define NB     256
#define TOPK   10
#define CAP    2048
#define SPER   64          // sample points per slice; 256 slices -> 16384 sample
#define MARGIN 2.0f        // bf16 worst-case score err ~0.5; 4x headroom
#define FPTS   128         // points per k_filter block
#define FGRID  ((NPTS + FPTS - 1) / FPTS)   // 3907
#define QS     52          // LDS row stride in bf16 (104 B: 8-B aligned, 2-way banks)
#define LCAP   8           // per-(block,query) local candidate cap (lambda~0.23)

typedef short v4s  __attribute__((ext_vector_type(4)));
typedef short v8s  __attribute__((ext_vector_type(8)));
typedef float v16f __attribute__((ext_vector_type(16)));

__device__ __forceinline__ unsigned short f2bf(float f) {   // round-to-nearest-even
    unsigned u = __float_as_uint(f);
    unsigned r = u + 0x7FFFu + ((u >> 16) & 1u);
    return (unsigned short)(r >> 16);
}
__device__ __forceinline__ float bf2f(unsigned short h) {
    return __uint_as_float(((unsigned)h) << 16);
}

// --- exact fp32 pieces: bitwise-identical order in k_sample and k_final -----
__device__ __forceinline__ float norm34(const float* __restrict__ r) {
    float a0 = 0.f, a1 = 0.f, a2 = 0.f, a3 = 0.f;
#pragma unroll
    for (int d = 0; d < 32; d += 4) {
        a0 = fmaf(r[d + 0], r[d + 0], a0);
        a1 = fmaf(r[d + 1], r[d + 1], a1);
        a2 = fmaf(r[d + 2], r[d + 2], a2);
        a3 = fmaf(r[d + 3], r[d + 3], a3);
    }
    a0 = fmaf(r[32], r[32], a0);
    a1 = fmaf(r[33], r[33], a1);
    return (a0 + a1) + (a2 + a3);
}
__device__ __forceinline__ float dot34(const float* __restrict__ r, const float* q) {
    float a0 = 0.f, a1 = 0.f, a2 = 0.f, a3 = 0.f;
#pragma unroll
    for (int d = 0; d < 32; d += 4) {
        a0 = fmaf(r[d + 0], q[d + 0], a0);
        a1 = fmaf(r[d + 1], q[d + 1], a1);
        a2 = fmaf(r[d + 2], q[d + 2], a2);
        a3 = fmaf(r[d + 3], q[d + 3], a3);
    }
    a0 = fmaf(r[32], q[32], a0);
    a1 = fmaf(r[33], q[33], a1);
    return (a0 + a1) + (a2 + a3);
}
// float4 LDS variant with IDENTICAL fma order (a0..a3 rotation + tail) so the
// resulting s is bitwise equal to dot34 on the same values.
__device__ __forceinline__ float dot34_v4(const float4* __restrict__ r4, const float* q) {
    float a0 = 0.f, a1 = 0.f, a2 = 0.f, a3 = 0.f;
#pragma unroll
    for (int dp = 0; dp < 8; ++dp) {
        float4 v = r4[dp];
        a0 = fmaf(v.x, q[4 * dp + 0], a0);
        a1 = fmaf(v.y, q[4 * dp + 1], a1);
        a2 = fmaf(v.z, q[4 * dp + 2], a2);
        a3 = fmaf(v.w, q[4 * dp + 3], a3);
    }
    float2 t = *(const float2*)(r4 + 8);
    a0 = fmaf(t.x, q[32], a0);
    a1 = fmaf(t.y, q[33], a1);
    return (a0 + a1) + (a2 + a3);
}
__device__ __forceinline__ void load_q(const float* __restrict__ obs,
                                       const float* __restrict__ act, int b, float* q) {
#pragma unroll
    for (int d = 0; d < 32; ++d) q[d] = obs[b * 32 + d];
    q[32] = act[b * 2 + 0];
    q[33] = act[b * 2 + 1];
}

// --- kernel 0a: per-(query, 64-pt slice) min of s over 16384-pt sample ------
__global__ __launch_bounds__(256, 4) void k_sample(const float* __restrict__ obs,
                                                   const float* __restrict__ act,
                                                   const float* __restrict__ msa,
                                                   float* __restrict__ minima) {
    __shared__ __align__(16) float sm[SPER * 36];   // stride 36 -> 16-B rows
    __shared__ float smn[SPER];
    const int g = blockIdx.x, t = threadIdx.x;
    const int base = g * SPER;
    for (int i = t; i < SPER * 34; i += 256) {      // coalesced copy
        int row = i / 34, d = i - row * 34;
        sm[row * 36 + d] = msa[(size_t)base * 34 + i];
    }
    __syncthreads();
    if (t < SPER) smn[t] = norm34(&sm[t * 36]);     // exact fp32 norms
    __syncthreads();
    float q[34];
    load_q(obs, act, t, q);
    float best = __builtin_inff();
#pragma unroll 2
    for (int j = 0; j < SPER; ++j) {
        float s = fmaf(-2.f, dot34_v4((const float4*)&sm[j * 36], q), smn[j]);
        best = fminf(best, s);
    }
    minima[g * NB + t] = best;
}

// --- kernel 0b: tau = 10th smallest slice-min; zero counts; emit q-hat bf16 -
__global__ __launch_bounds__(64) void k_tau(const float* __restrict__ minima,
                                            const float* __restrict__ obs,
                                            const float* __restrict__ act,
                                            unsigned short* __restrict__ qbf,
                                            int* __restrict__ count) {
    const int b = blockIdx.x, lane = threadIdx.x;
    if (lane == 0) count[b] = 0;
    float v[4];
#pragma unroll
    for (int k = 0; k < 4; ++k) v[k] = minima[(lane + 64 * k) * NB + b];
    float last = 0.f;
    for (int r = 0; r < TOPK; ++r) {
        float lm = v[0]; int la = 0;
#pragma unroll
        for (int k = 1; k < 4; ++k) { if (v[k] < lm) { lm = v[k]; la = k; } }
        float wm = lm;
        for (int off = 32; off; off >>= 1) wm = fminf(wm, __shfl_xor(wm, off));
        unsigned long long msk = __ballot(lm == wm);
        int first = (int)__builtin_ctzll(msk);
        if (lane == first) {
#pragma unroll
            for (int k = 0; k < 4; ++k) { if (k == la) v[k] = __builtin_inff(); }
        }
        last = wm;   // wave-uniform
    }
    float val = 0.f;
    if (lane < 32)       val = obs[b * 32 + lane];
    else if (lane < 34)  val = act[b * 2 + (lane - 32)];
    else if (lane == 34) val = -0.5f;
    else if (lane == 35) val = 0.5f * (last + MARGIN);
    unsigned short h = (lane < 36) ? f2bf(val) : (unsigned short)0;
    if (lane < QS) qbf[b * QS + lane] = h;
}

// --- kernel 1: MFMA bf16 filter, LDS-compacted candidate append -------------
// acc[q][p] = q.m - 0.5*|m|^2 + (tau_q+MARGIN)/2 ;  candidate iff acc >= 0
__global__ __launch_bounds__(256, 3) void k_filter(const float* __restrict__ msa,
                                                   const unsigned short* __restrict__ qbf,
                                                   int* __restrict__ count,
                                                   int* __restrict__ cand_i) {
    __shared__ __align__(16) unsigned short lq[NB * QS];    // 26624 B
    __shared__ __align__(16) unsigned short lm[FPTS * QS];  // 13312 B
    __shared__ int lcount[NB];                              // 1024 B
    __shared__ int lcand[NB * LCAP];                        // 8192 B
    const int g = blockIdx.x, t = threadIdx.x;
    const int lo = g * FPTS;
    // stage Q-hat (pre-converted bf16) as float4
    const float4* qsrc = (const float4*)qbf;
    for (int i = t; i < NB * QS / 8; i += 256)
        *(float4*)&lq[i * 8] = qsrc[i];
    // stage M chunk: 128 rows x 17 float2, convert to bf16
    for (int i = t; i < FPTS * 17; i += 256) {
        int row = i / 17, dp = i - row * 17;
        int gp = lo + row;
        float2 v = make_float2(0.f, 0.f);
        if (gp < NPTS) v = *(const float2*)&msa[(size_t)gp * 34 + 2 * dp];
        ushort2 h; h.x = f2bf(v.x); h.y = f2bf(v.y);
        *(ushort2*)&lm[row * QS + 2 * dp] = h;
    }
    lcount[t] = 0;
    __syncthreads();
    // norm pass on the bf16 values MFMA will see; pad dims
    if (t < FPTS) {
        float nrm = 0.f;
#pragma unroll
        for (int dp = 0; dp < 17; ++dp) {
            ushort2 h = *(const ushort2*)&lm[t * QS + 2 * dp];
            float f0 = bf2f(h.x), f1 = bf2f(h.y);
            nrm = fmaf(f0, f0, nrm);
            nrm = fmaf(f1, f1, nrm);
        }
        bool valid = (lo + t < NPTS);
        lm[t * QS + 34] = f2bf(valid ? nrm : 1e30f);
        lm[t * QS + 35] = valid ? (unsigned short)0x3F80 : (unsigned short)0;
        *(ushort4*)&lm[t * QS + 36] = make_ushort4(0, 0, 0, 0);
        *(ushort4*)&lm[t * QS + 40] = make_ushort4(0, 0, 0, 0);
        *(ushort4*)&lm[t * QS + 44] = make_ushort4(0, 0, 0, 0);
    }
    __syncthreads();
    const int w = t >> 6, lane = t & 63;
    const int mrow = lane & 31, half = lane >> 5;
    const int p = lo + w * 32 + mrow;               // this lane's point
    // B fragment: wave w owns points [w*32, w*32+32)
    const unsigned short* mrp = &lm[(w * 32 + mrow) * QS + half * 8];
    v8s B[3];
#pragma unroll
    for (int s = 0; s < 3; ++s) {
        v4s blo = *(const v4s*)(mrp + 16 * s);
        v4s bhi = *(const v4s*)(mrp + 16 * s + 4);
        B[s] = __builtin_shufflevector(blo, bhi, 0, 1, 2, 3, 4, 5, 6, 7);
    }
#pragma unroll
    for (int qt = 0; qt < 8; ++qt) {
        const unsigned short* qrow = &lq[(qt * 32 + mrow) * QS + half * 8];
        v16f acc;
#pragma unroll
        for (int i = 0; i < 16; ++i) acc[i] = 0.f;
#pragma unroll
        for (int s = 0; s < 3; ++s) {
            v4s alo = *(const v4s*)(qrow + 16 * s);
            v4s ahi = *(const v4s*)(qrow + 16 * s + 4);
            v8s A = __builtin_shufflevector(alo, ahi, 0, 1, 2, 3, 4, 5, 6, 7);
            acc = __builtin_amdgcn_mfma_f32_32x32x16_bf16(A, B[s], acc, 0, 0, 0);
        }
        // packed per-lane hit bitmask; branch only for real hits
        unsigned hm = 0;
#pragma unroll
        for (int r = 0; r < 16; ++r) hm |= (acc[r] >= 0.f) ? (1u << r) : 0u;
        while (hm) {
            int r = __builtin_ctz(hm);
            hm &= hm - 1;
            // C/D: col(point)=lane&31, row(query)=(r&3)+8*(r>>2)+4*half
            int qq = qt * 32 + (r & 3) + 8 * (r >> 2) + 4 * half;
            int slot = atomicAdd(&lcount[qq], 1);
            if (slot < LCAP) {
                lcand[qq * LCAP + slot] = p;
            } else {                                // overflow fallback (rare)
                int gs = atomicAdd(count + qq, 1);
                if (gs < CAP) cand_i[(size_t)qq * CAP + gs] = p;
            }
        }
    }
    __syncthreads();
    // flush: one global atomic per query with hits, compacted writes
    int n = lcount[t];
    if (n > LCAP) n = LCAP;
    if (n > 0) {
        int base = atomicAdd(count + t, n);
        for (int i = 0; i < n; ++i) {
            int g2 = base + i;
            if (g2 < CAP) cand_i[(size_t)t * CAP + g2] = lcand[t * LCAP + i];
        }
    }
}

// --- kernel 2: exact fp32 refine of candidates + top-10 + softmax -----------
__global__ __launch_bounds__(256) void k_final(const float* __restrict__ obs,
                                               const float* __restrict__ act,
                                               const float* __restrict__ msa,
                                               const int* __restrict__ cand_i,
                                               const int* __restrict__ count,
                                               const float* __restrict__ memQ,
                                               float* __restrict__ out) {
    __shared__ float ls[CAP];
    __shared__ int   li[CAP];
    __shared__ float rs[4];
    __shared__ int   ri[4];
    __shared__ float sel_s[TOPK];
    __shared__ int   sel_i[TOPK];
    const int b = blockIdx.x, t = threadIdx.x;
    const int lane = t & 63, wid = t >> 6;
    int cnt = count[b];
    if (cnt > CAP) cnt = CAP;
    float q[34];
    load_q(obs, act, b, q);
    for (int j = t; j < cnt; j += 256) {            // exact fp32 re-scores
        int idx = cand_i[(size_t)b * CAP + j];
        const float* row = msa + (size_t)idx * 34;
        ls[j] = fmaf(-2.f, dot34(row, q), norm34(row));
        li[j] = idx;
    }
    __syncthreads();
    for (int k = 0; k < TOPK; ++k) {
        float bs = __builtin_inff();
        int   bi = 0x7fffffff;
        for (int j = t; j < cnt; j += 256) {
            float s = ls[j]; int i = li[j];
            if (s < bs || (s == bs && i < bi)) { bs = s; bi = i; }
        }
        for (int off = 32; off; off >>= 1) {
            float s2 = __shfl_down(bs, off);
            int   i2 = __shfl_down(bi, off);
            if (s2 < bs || (s2 == bs && i2 < bi)) { bs = s2; bi = i2; }
        }
        if (lane == 0) { rs[wid] = bs; ri[wid] = bi; }
        __syncthreads();
        if (t == 0) {
            float fs = rs[0]; int fi = ri[0];
#pragma unroll
            for (int ww = 1; ww < 4; ++ww) {
                if (rs[ww] < fs || (rs[ww] == fs && ri[ww] < fi)) { fs = rs[ww]; fi = ri[ww]; }
            }
            sel_s[k] = fs; sel_i[k] = fi;
        }
        __syncthreads();
        const int win = sel_i[k];
        for (int j = t; j < cnt; j += 256) {
            if (li[j] == win) ls[j] = __builtin_inff();
        }
        __syncthreads();
    }
    if (t == 0) {
        float m = sel_s[TOPK - 1];
        float wsum = 0.f, acc = 0.f;
#pragma unroll
        for (int k = 0; k < TOPK; ++k) {
            if (sel_i[k] == 0x7fffffff) continue;
            float w2 = expf(sel_s[k] - m);
            wsum += w2;
            acc = fmaf(w2, memQ[sel_i[k]], acc);
        }
        out[b] = acc / wsum;
    }
}

extern "C" void kernel_launch(void* const* d_in, const int* in_sizes, int n_in,
                              void* d_out, int out_size, void* d_ws, size_t ws_size,
                              hipStream_t stream) {
    const float* obs = (const float*)d_in[0];   // [256,32]
    const float* act = (const float*)d_in[1];   // [256,2]
    const float* msa = (const float*)d_in[2];   // [500000,34]
    const float* mq  = (const float*)d_in[3];   // [500000,1]
    float* out = (float*)d_out;                 // [256]

    char* ws = (char*)d_ws;
    unsigned short* qbf = (unsigned short*)ws;              // 26624 B
    int*   count  = (int*)(ws + 26624);                     // 1024 B
    float* minima = (float*)(ws + 27648);                   // 262144 B
    int*   cand_i = (int*)(ws + 27648 + 262144);            // 2 MB

    k_sample<<<NB, 256, 0, stream>>>(obs, act, msa, minima);
    k_tau   <<<NB, 64, 0, stream>>>(minima, obs, act, qbf, count);
    k_filter<<<FGRID, 256, 0, stream>>>(msa, qbf, count, cand_i);
    k_final <<<NB, 256, 0, stream>>>(obs, act, msa, cand_i, count, mq, out);
}